// Round 7
// baseline (852.052 us; speedup 1.0000x reference)
//
#include <hip/hip_runtime.h>
#include <math.h>

#define N_NODES 50000
#define N_EDGES 1200000
#define F 64
#define CAP 49            // bucket capacity per node
#define OVF_MAX 1024
#define NBIN 196          // bins of 256 nodes (dst >> 8)
#define BIN_NODES 256
#define CAP_BIN 7680      // mean 6144 + 20 sigma

// ws layout (bytes):
//   s       [0,       200000)    float[50000]
//   dd      [200000,  400000)    float[50000]
//   cnt     [400000,  600000)    int[50000]      true degree (from k_bucket)
//   bin_cnt [600000,  601024)    int[196]+pad
//   ovf_cnt [601024,  601280)    int+pad
//   ovf     [601280,  605376)    uint[1024]      (dst<<16)|src
//   bucket  [605376,  5505376)   ushort[50000*49]
//   region X[5505376, 11905376)  time-shared:
//       phase 1: binned uint[196*7680] = 6,021,120 B (k_bin -> k_bucket)
//       phase 2: fb ushort[50000*64]  = 6,400,000 B (k_bf16 -> k_fused)
// total 11,905,376 B (< 12,001,024 proven safe)

__device__ __forceinline__ unsigned short f32_to_bf16_rne(float f) {
    unsigned u = __float_as_uint(f);
    return (unsigned short)((u + 0x7FFFu + ((u >> 16) & 1u)) >> 16);
}
__device__ __forceinline__ float bf16_to_f32(unsigned short u) {
    return __uint_as_float(((unsigned)u) << 16);
}

// A: per-node attention dots + zero bin/ovf counters. One wave per node.
__global__ void k_prep(const float* __restrict__ feature,
                       const float* __restrict__ attn_w,
                       float* __restrict__ s, float* __restrict__ dd,
                       int* __restrict__ bin_cnt, int* __restrict__ ovf_cnt) {
    int gid = blockIdx.x * blockDim.x + threadIdx.x;
    if (gid < NBIN) bin_cnt[gid] = 0;
    if (gid == NBIN) *ovf_cnt = 0;
    int wave = gid >> 6;
    int lane = threadIdx.x & 63;
    if (wave >= N_NODES) return;
    float f = feature[wave * F + lane];
    float sv = f * attn_w[lane];
    float dv = f * attn_w[F + lane];
    #pragma unroll
    for (int o = 32; o > 0; o >>= 1) {
        sv += __shfl_down(sv, o, 64);
        dv += __shfl_down(dv, o, 64);
    }
    if (lane == 0) {
        s[wave] = sv;
        dd[wave] = dv;
    }
}

// B: bin edges by dst>>8; packed (dst<<16)|src. Sequential positions per bin
// => L2 merges writes into full lines.
__global__ void k_bin(const int* __restrict__ src, const int* __restrict__ dst,
                      int* __restrict__ bin_cnt, unsigned* __restrict__ binned) {
    int i = blockIdx.x * blockDim.x + threadIdx.x;
    if (i >= N_EDGES / 4) return;
    int4 d4 = ((const int4*)dst)[i];
    int4 s4 = ((const int4*)src)[i];
    int dv[4] = {d4.x, d4.y, d4.z, d4.w};
    int sv[4] = {s4.x, s4.y, s4.z, s4.w};
    #pragma unroll
    for (int u = 0; u < 4; u++) {
        int b = dv[u] >> 8;
        int pos = atomicAdd(&bin_cnt[b], 1);
        if (pos < CAP_BIN)
            binned[(size_t)b * CAP_BIN + pos] =
                (((unsigned)dv[u]) << 16) | (unsigned)sv[u];
    }
}

// C: one workgroup per bin — build the bin's buckets in LDS (LDS atomics),
// stream out coalesced uint4, write true degrees.
__global__ __launch_bounds__(256) void k_bucket(
        const unsigned* __restrict__ binned, const int* __restrict__ bin_cnt,
        int* __restrict__ cnt, unsigned short* __restrict__ bucket,
        int* __restrict__ ovf_cnt, unsigned* __restrict__ ovf) {
    __shared__ int cnt_l[BIN_NODES];
    __shared__ __align__(16) unsigned short buck_l[BIN_NODES * CAP];
    int bin = blockIdx.x;
    int t = threadIdx.x;
    int n0 = bin << 8;
    int nn = N_NODES - n0; if (nn > BIN_NODES) nn = BIN_NODES;
    cnt_l[t] = 0;
    __syncthreads();
    int E = bin_cnt[bin];
    if (E > CAP_BIN) E = CAP_BIN;
    const unsigned* be = binned + (size_t)bin * CAP_BIN;
    for (int i = t; i < E; i += 256) {
        unsigned v = be[i];
        int local = (v >> 16) & 255;
        int sid = (int)(v & 0xFFFFu);
        int r = atomicAdd(&cnt_l[local], 1);
        if (r < CAP) {
            buck_l[local * CAP + r] = (unsigned short)sid;
        } else {
            int o = atomicAdd(ovf_cnt, 1);
            if (o < OVF_MAX)
                ovf[o] = ((unsigned)(n0 + local) << 16) | (unsigned)sid;
        }
    }
    __syncthreads();
    if (t < nn) cnt[n0 + t] = cnt_l[t];
    int nu4 = (nn * CAP * 2) >> 4;                 // 16B chunks (divides exactly)
    const uint4* bl4 = (const uint4*)buck_l;
    uint4* bg4 = (uint4*)(bucket + (size_t)n0 * CAP);
    for (int i = t; i < nu4; i += 256) bg4[i] = bl4[i];
}

// D: bf16 copy of feature table (overwrites binned region).
__global__ void k_bf16(const float* __restrict__ feature,
                       unsigned short* __restrict__ fb) {
    int i = blockIdx.x * blockDim.x + threadIdx.x;
    if (i >= (N_NODES * F) / 4) return;
    float4 f = ((const float4*)feature)[i];
    ushort4 o;
    o.x = f32_to_bf16_rne(f.x);
    o.y = f32_to_bf16_rne(f.y);
    o.z = f32_to_bf16_rne(f.z);
    o.w = f32_to_bf16_rne(f.w);
    ((ushort4*)fb)[i] = o;
}

// E: fused aggregate + projection. 8 nodes / 512-thread block, 1 wave/node.
// Softmax single-chunk (deg<=49<64). Gather: lanes 0-31 handle even edge,
// lanes 32-63 odd edge — 1 dword/lane = 2 bf16 = half a row; 8 loads in
// flight cover 16 edges. Combine halves with shfl_xor(32).
__global__ __launch_bounds__(512, 8) void k_fused(
        const unsigned short* __restrict__ bucket,
        const int* __restrict__ cnt,
        const float* __restrict__ s, const float* __restrict__ dd,
        const unsigned short* __restrict__ fb,
        const float* __restrict__ feature,
        const float* __restrict__ lin_w, const float* __restrict__ lin_b,
        float* __restrict__ out) {
    __shared__ float Wl[64 * 129];
    __shared__ float xl[8][128];
    int t = threadIdx.x;
    for (int i = t; i < 64 * 128; i += 512) {
        Wl[(i >> 7) * 129 + (i & 127)] = lin_w[i];
    }
    __syncthreads();

    int wid = t >> 6, lane = t & 63;
    int n = blockIdx.x * 8 + wid;       // grid exact: 6250*8 = 50000
    int deg = cnt[n];
    if (deg > CAP) return;              // wave-uniform; k_cleanup owns these
    const unsigned* fb32 = (const unsigned*)fb;
    if (deg > 0) {
        int si = 0;
        float ev = -1e30f;
        if (lane < deg) {
            si = (int)bucket[n * CAP + lane];
            float v = s[si] + dd[n];
            ev = v > 0.0f ? v : 0.01f * v;
        }
        float m = ev;
        #pragma unroll
        for (int o = 32; o > 0; o >>= 1)
            m = fmaxf(m, __shfl_xor(m, o, 64));
        float p = (lane < deg) ? __expf(ev - m) : 0.0f;
        float l = p;
        #pragma unroll
        for (int o = 32; o > 0; o >>= 1)
            l += __shfl_xor(l, o, 64);
        p *= __builtin_amdgcn_rcpf(l);
        int half = lane >> 5;           // which of the 2 edges per load step
        int col  = lane & 31;           // dword column within the row
        float acc0 = 0.0f, acc1 = 0.0f;
        for (int k = 0; k < deg; k += 16) {
            unsigned fv[8];
            #pragma unroll
            for (int u = 0; u < 8; u++) {
                int sk = __shfl(si, k + 2 * u + half, 64);
                fv[u] = fb32[sk * 32 + col];
            }
            #pragma unroll
            for (int u = 0; u < 8; u++) {
                float pw = __shfl(p, k + 2 * u + half, 64);  // 0 beyond deg
                acc0 = fmaf(pw, __uint_as_float(fv[u] << 16), acc0);
                acc1 = fmaf(pw, __uint_as_float(fv[u] & 0xFFFF0000u), acc1);
            }
        }
        acc0 += __shfl_xor(acc0, 32, 64);
        acc1 += __shfl_xor(acc1, 32, 64);
        if (lane < 32) {                // lanes 0-31 hold features 2c, 2c+1
            xl[wid][64 + 2 * col]     = acc0;
            xl[wid][64 + 2 * col + 1] = acc1;
        }
    } else {
        xl[wid][64 + lane] = 0.0f;
    }
    xl[wid][lane] = feature[n * F + lane];
    float oa = lin_b[lane];
    #pragma unroll
    for (int k = 0; k < 128; k++)
        oa += xl[wid][k] * Wl[lane * 129 + k];
    out[n * F + lane] = fmaxf(oa, 0.0f);
}

// F: overflow cleanup — one block, handles nodes with deg > CAP exactly.
__global__ __launch_bounds__(256) void k_cleanup(
        const unsigned short* __restrict__ bucket,
        const int* __restrict__ cnt,
        const int* __restrict__ ovf_cnt, const unsigned int* __restrict__ ovf,
        const float* __restrict__ s, const float* __restrict__ dd,
        const unsigned short* __restrict__ fb,
        const float* __restrict__ feature,
        const float* __restrict__ lin_w, const float* __restrict__ lin_b,
        float* __restrict__ out) {
    int M = *ovf_cnt;
    if (M > OVF_MAX) M = OVF_MAX;
    if (M == 0) return;                  // uniform, before any barrier
    __shared__ float Wl[64 * 129];
    __shared__ int list[128];
    __shared__ int nlist;
    __shared__ unsigned short edg[4][256];
    __shared__ float xc[4][128];
    int t = threadIdx.x;
    for (int i = t; i < 64 * 128; i += 256)
        Wl[(i >> 7) * 129 + (i & 127)] = lin_w[i];
    if (t == 0) {
        nlist = 0;
        for (int i = 0; i < M; i++) {
            int d = (int)(ovf[i] >> 16);
            bool seen = false;
            for (int j = 0; j < nlist; j++) if (list[j] == d) seen = true;
            if (!seen && nlist < 128) list[nlist++] = d;
        }
    }
    __syncthreads();
    int wid = t >> 6, lane = t & 63;
    for (int idx = wid; idx < nlist; idx += 4) {
        int n = list[idx];
        int deg = cnt[n];
        if (lane < CAP) edg[wid][lane] = bucket[n * CAP + lane];
        int k2 = CAP;
        for (int base = 0; base < M; base += 64) {
            int i2 = base + lane;
            unsigned val = 0;
            bool mt = false;
            if (i2 < M) { val = ovf[i2]; mt = ((int)(val >> 16) == n); }
            unsigned long long mask = __ballot(mt);
            if (mt) {
                int pos = k2 + __popcll(mask & ((1ULL << lane) - 1ULL));
                if (pos < 256) edg[wid][pos] = (unsigned short)(val & 0xFFFFu);
            }
            k2 += __popcll(mask);
        }
        __threadfence_block();
        int nd = deg < 256 ? deg : 256;
        float m = -1e30f, l = 0.0f, acc = 0.0f;
        float dn = dd[n];
        for (int c0 = 0; c0 < nd; c0 += 64) {
            int j = c0 + lane;
            int sid = 0;
            float ev = -1e30f;
            if (j < nd) {
                sid = (int)edg[wid][j];
                float v = s[sid] + dn;
                ev = v > 0.0f ? v : 0.01f * v;
            }
            float cm = ev;
            #pragma unroll
            for (int o = 32; o > 0; o >>= 1)
                cm = fmaxf(cm, __shfl_xor(cm, o, 64));
            float np = (j < nd) ? __expf(ev - cm) : 0.0f;
            float cl = np;
            #pragma unroll
            for (int o = 32; o > 0; o >>= 1)
                cl += __shfl_xor(cl, o, 64);
            float cacc = 0.0f;
            int c = nd - c0; if (c > 64) c = 64;
            for (int k = 0; k < c; k += 16) {
                float fv[16];
                #pragma unroll
                for (int u = 0; u < 16; u++) {
                    int sk = __builtin_amdgcn_readlane(sid, k + u);
                    fv[u] = bf16_to_f32(fb[sk * F + lane]);
                }
                #pragma unroll
                for (int u = 0; u < 16; u++) {
                    float pk = __uint_as_float(
                        __builtin_amdgcn_readlane(__float_as_uint(np), k + u));
                    cacc = fmaf(pk, fv[u], cacc);
                }
            }
            float mn = fmaxf(m, cm);
            float sc = __expf(m - mn);
            float sc2 = __expf(cm - mn);
            l = l * sc + cl * sc2;
            acc = acc * sc + cacc * sc2;
            m = mn;
        }
        float hm = acc / l;
        xc[wid][lane] = feature[n * F + lane];
        xc[wid][64 + lane] = hm;
        __threadfence_block();
        float oa = lin_b[lane];
        #pragma unroll
        for (int k = 0; k < 128; k++)
            oa += xc[wid][k] * Wl[lane * 129 + k];
        out[n * F + lane] = fmaxf(oa, 0.0f);
    }
}

extern "C" void kernel_launch(void* const* d_in, const int* in_sizes, int n_in,
                              void* d_out, int out_size, void* d_ws, size_t ws_size,
                              hipStream_t stream) {
    const float* feature = (const float*)d_in[0];
    const float* attn_w  = (const float*)d_in[1];
    const float* lin_w   = (const float*)d_in[2];
    const float* lin_b   = (const float*)d_in[3];
    const int*   src     = (const int*)d_in[4];
    const int*   dst     = (const int*)d_in[5];
    float* out = (float*)d_out;
    char* ws = (char*)d_ws;

    float*          s       = (float*)(ws);
    float*          dd      = (float*)(ws + 200000);
    int*            cnt     = (int*)  (ws + 400000);
    int*            bin_cnt = (int*)  (ws + 600000);
    int*            ovf_cnt = (int*)  (ws + 601024);
    unsigned*       ovf     = (unsigned*)(ws + 601280);
    unsigned short* bucket  = (unsigned short*)(ws + 605376);
    unsigned*       binned  = (unsigned*)(ws + 5505376);            // phase 1
    unsigned short* fb      = (unsigned short*)(ws + 5505376);      // phase 2

    k_prep<<<(N_NODES * 64) / 256, 256, 0, stream>>>(
        feature, attn_w, s, dd, bin_cnt, ovf_cnt);
    k_bin<<<(N_EDGES / 4 + 255) / 256, 256, 0, stream>>>(
        src, dst, bin_cnt, binned);
    k_bucket<<<NBIN, 256, 0, stream>>>(
        binned, bin_cnt, cnt, bucket, ovf_cnt, ovf);
    k_bf16<<<(N_NODES * F / 4 + 255) / 256, 256, 0, stream>>>(feature, fb);
    k_fused<<<N_NODES / 8, 512, 0, stream>>>(
        bucket, cnt, s, dd, fb, feature, lin_w, lin_b, out);
    k_cleanup<<<1, 256, 0, stream>>>(
        bucket, cnt, ovf_cnt, ovf, s, dd, fb, feature, lin_w, lin_b, out);
}

// Round 8
// 160.443 us; speedup vs baseline: 5.3106x; 5.3106x over previous
//
#include <hip/hip_runtime.h>
#include <math.h>

#define N_NODES 50000
#define N_EDGES 1200000
#define F 64
#define CAP 49            // per-node bucket capacity (P(deg>49) ~ 2.5e-6/node)
#define OVF_MAX 1024
#define NBIN 196          // bins of 256 nodes (dst >> 8)
#define BSTR 16           // bin_cnt stride in ints (64B) - no line sharing
#define CAP_BIN 7680      // mean 6122 + ~20 sigma
#define TILE 8192         // edges per k_bin workgroup
#define NTILE ((N_EDGES + TILE - 1) / TILE)   // 147

typedef __attribute__((ext_vector_type(8))) short short8;
typedef __attribute__((ext_vector_type(4))) float v4f;

// ws layout (bytes):
//   s       [0,       200000)    float[50000]
//   dd      [200000,  400000)    float[50000]
//   cnt     [400000,  600000)    int[50000]      true degree (k_bucket)
//   bin_cnt [600000,  612544)    int[196*16]     strided counters
//   ovf_cnt [612544,  612608)    int + pad
//   ovf     [612608,  616704)    uint[1024]      (dst<<16)|src
//   bucket  [616704,  5516704)   ushort[50000*49]
//   binned  [5516704, 11537824)  uint[196*7680]
// total 11,537,824 B (< 11.9M proven safe)

__device__ __forceinline__ unsigned short f32_to_bf16_rne(float f) {
    unsigned u = __float_as_uint(f);
    return (unsigned short)((u + 0x7FFFu + ((u >> 16) & 1u)) >> 16);
}

// A: per-node attention dots + zero counters. One wave per node.
__global__ void k_prep(const float* __restrict__ feature,
                       const float* __restrict__ attn_w,
                       float* __restrict__ s, float* __restrict__ dd,
                       int* __restrict__ bin_cnt, int* __restrict__ ovf_cnt) {
    int gid = blockIdx.x * blockDim.x + threadIdx.x;
    if (gid < NBIN * BSTR) bin_cnt[gid] = 0;
    if (gid == NBIN * BSTR) *ovf_cnt = 0;
    int wave = gid >> 6;
    int lane = threadIdx.x & 63;
    if (wave >= N_NODES) return;
    float f = feature[wave * F + lane];
    float sv = f * attn_w[lane];
    float dv = f * attn_w[F + lane];
    #pragma unroll
    for (int o = 32; o > 0; o >>= 1) {
        sv += __shfl_down(sv, o, 64);
        dv += __shfl_down(dv, o, 64);
    }
    if (lane == 0) {
        s[wave] = sv;
        dd[wave] = dv;
    }
}

// B: LDS-staged binning. Per 8192-edge tile: count -> scan -> place in LDS,
// ONE global atomic per (tile,bin) to reserve, coalesced flush.
__global__ __launch_bounds__(256) void k_bin(
        const int* __restrict__ src, const int* __restrict__ dst,
        int* __restrict__ bin_cnt, unsigned* __restrict__ binned) {
    __shared__ unsigned ord[TILE];
    __shared__ int cnt_l[NBIN], off_l[NBIN], cur_l[NBIN], base_g[NBIN];
    __shared__ int buf[256];
    int t = threadIdx.x;
    int e0 = blockIdx.x * TILE;
    int ecnt = N_EDGES - e0; if (ecnt > TILE) ecnt = TILE;
    for (int i = t; i < NBIN; i += 256) cnt_l[i] = 0;
    __syncthreads();
    int n4 = ecnt >> 2;      // int4 groups this tile (2048 or 992; both exact)
    const int4* s4p = (const int4*)src + (e0 >> 2);
    const int4* d4p = (const int4*)dst + (e0 >> 2);
    // pass 1: count
    for (int c = t; c < n4; c += 256) {
        int4 d4 = d4p[c];
        atomicAdd(&cnt_l[d4.x >> 8], 1);
        atomicAdd(&cnt_l[d4.y >> 8], 1);
        atomicAdd(&cnt_l[d4.z >> 8], 1);
        atomicAdd(&cnt_l[d4.w >> 8], 1);
    }
    __syncthreads();
    // exclusive scan over NBIN (Hillis-Steele across 256 threads)
    int v0 = (t < NBIN) ? cnt_l[t] : 0;
    buf[t] = v0;
    __syncthreads();
    #pragma unroll
    for (int d = 1; d < 256; d <<= 1) {
        int x = (t >= d) ? buf[t - d] : 0;
        __syncthreads();
        buf[t] += x;
        __syncthreads();
    }
    if (t < NBIN) {
        int off = buf[t] - v0;
        off_l[t] = off;
        cur_l[t] = off;
        base_g[t] = atomicAdd(&bin_cnt[t * BSTR], v0);  // bulk reserve
    }
    __syncthreads();
    // pass 2: re-read (L2 hot) and place into LDS in bin order
    for (int c = t; c < n4; c += 256) {
        int4 d4 = d4p[c];
        int4 s4 = s4p[c];
        int dv[4] = {d4.x, d4.y, d4.z, d4.w};
        int sv[4] = {s4.x, s4.y, s4.z, s4.w};
        #pragma unroll
        for (int u = 0; u < 4; u++) {
            int r = atomicAdd(&cur_l[dv[u] >> 8], 1);
            ord[r] = (((unsigned)dv[u]) << 16) | (unsigned)sv[u];
        }
    }
    __syncthreads();
    // flush: consecutive LDS positions -> consecutive global positions per bin
    for (int i = t; i < ecnt; i += 256) {
        unsigned v = ord[i];
        int b = v >> 24;
        int pos = base_g[b] + (i - off_l[b]);
        if (pos < CAP_BIN) binned[(size_t)b * CAP_BIN + pos] = v;
    }
}

// C: one workgroup per bin — build per-node buckets in LDS, coalesced out.
__global__ __launch_bounds__(256) void k_bucket(
        const unsigned* __restrict__ binned, const int* __restrict__ bin_cnt,
        int* __restrict__ cnt, unsigned short* __restrict__ bucket,
        int* __restrict__ ovf_cnt, unsigned* __restrict__ ovf) {
    __shared__ int cnt_l[256];
    __shared__ __align__(16) unsigned short buck_l[256 * CAP];
    int bin = blockIdx.x;
    int t = threadIdx.x;
    int n0 = bin << 8;
    int nn = N_NODES - n0; if (nn > 256) nn = 256;
    cnt_l[t] = 0;
    __syncthreads();
    int E = bin_cnt[bin * BSTR];
    if (E > CAP_BIN) E = CAP_BIN;
    const unsigned* be = binned + (size_t)bin * CAP_BIN;
    for (int i = t; i < E; i += 256) {
        unsigned v = be[i];
        int local = (v >> 16) & 255;
        int sid = (int)(v & 0xFFFFu);
        int r = atomicAdd(&cnt_l[local], 1);
        if (r < CAP) {
            buck_l[local * CAP + r] = (unsigned short)sid;
        } else {
            int o = atomicAdd(ovf_cnt, 1);
            if (o < OVF_MAX)
                ovf[o] = ((unsigned)(n0 + local) << 16) | (unsigned)sid;
        }
    }
    __syncthreads();
    if (t < nn) cnt[n0 + t] = cnt_l[t];
    int nu4 = (nn * CAP * 2) >> 4;      // divides exactly (nn*98 % 16 == 0)
    const uint4* bl4 = (const uint4*)buck_l;
    uint4* bg4 = (uint4*)(bucket + (size_t)n0 * CAP);
    for (int i = t; i < nu4; i += 256) bg4[i] = bl4[i];
}

// D: aggregation only. 1 wave per node; softmax single-chunk (deg<=49);
// gather fp32 half-rows: lanes 0-31 even edge, 32-63 odd edge, float2/lane.
// Writes hm directly to d_out (k_proj overwrites in place).
__global__ __launch_bounds__(512) void k_aggregate(
        const unsigned short* __restrict__ bucket,
        const int* __restrict__ cnt,
        const float* __restrict__ s, const float* __restrict__ dd,
        const float* __restrict__ feature,
        float* __restrict__ out) {
    int t = threadIdx.x;
    int wid = t >> 6, lane = t & 63;
    int n = blockIdx.x * 8 + wid;        // grid exact: 6250*8 = 50000
    int deg = cnt[n];
    if (deg > CAP) return;               // k_cleanup writes these rows
    if (deg == 0) { out[n * F + lane] = 0.0f; return; }
    int si = 0;
    float ev = -1e30f;
    if (lane < deg) {
        si = (int)bucket[n * CAP + lane];
        float v = s[si] + dd[n];
        ev = v > 0.0f ? v : 0.01f * v;
    }
    float m = ev;
    #pragma unroll
    for (int o = 32; o > 0; o >>= 1)
        m = fmaxf(m, __shfl_xor(m, o, 64));
    float p = (lane < deg) ? __expf(ev - m) : 0.0f;
    float l = p;
    #pragma unroll
    for (int o = 32; o > 0; o >>= 1)
        l += __shfl_xor(l, o, 64);
    p *= __builtin_amdgcn_rcpf(l);
    int half = lane >> 5;
    int col = lane & 31;
    const float2* f2 = (const float2*)feature;
    float acc0 = 0.0f, acc1 = 0.0f;
    for (int k = 0; k < deg; k += 16) {   // pad lanes have p=0, si=0 (hot row)
        float2 fv[8];
        #pragma unroll
        for (int u = 0; u < 8; u++) {
            int sk = __shfl(si, k + 2 * u + half, 64);
            fv[u] = f2[sk * 32 + col];
        }
        #pragma unroll
        for (int u = 0; u < 8; u++) {
            float pw = __shfl(p, k + 2 * u + half, 64);
            acc0 = fmaf(pw, fv[u].x, acc0);
            acc1 = fmaf(pw, fv[u].y, acc1);
        }
    }
    acc0 += __shfl_xor(acc0, 32, 64);
    acc1 += __shfl_xor(acc1, 32, 64);
    if (lane < 32) {
        float2 st; st.x = acc0; st.y = acc1;
        ((float2*)out)[n * 32 + col] = st;
    }
}

// E: overflow cleanup — writes hm rows for nodes with deg > CAP (before proj).
__global__ __launch_bounds__(256) void k_cleanup(
        const unsigned short* __restrict__ bucket,
        const int* __restrict__ cnt,
        const int* __restrict__ ovf_cnt, const unsigned int* __restrict__ ovf,
        const float* __restrict__ s, const float* __restrict__ dd,
        const float* __restrict__ feature,
        float* __restrict__ out) {
    int M = *ovf_cnt;
    if (M > OVF_MAX) M = OVF_MAX;
    if (M == 0) return;                  // uniform, before any barrier
    __shared__ int list[128];
    __shared__ int nlist;
    __shared__ unsigned short edg[4][256];
    int t = threadIdx.x;
    if (t == 0) {
        nlist = 0;
        for (int i = 0; i < M; i++) {
            int d = (int)(ovf[i] >> 16);
            bool seen = false;
            for (int j = 0; j < nlist; j++) if (list[j] == d) seen = true;
            if (!seen && nlist < 128) list[nlist++] = d;
        }
    }
    __syncthreads();
    int wid = t >> 6, lane = t & 63;
    for (int idx = wid; idx < nlist; idx += 4) {
        int n = list[idx];
        int deg = cnt[n];
        if (lane < CAP) edg[wid][lane] = bucket[n * CAP + lane];
        int k2 = CAP;
        for (int base = 0; base < M; base += 64) {
            int i2 = base + lane;
            unsigned val = 0;
            bool mt = false;
            if (i2 < M) { val = ovf[i2]; mt = ((int)(val >> 16) == n); }
            unsigned long long mask = __ballot(mt);
            if (mt) {
                int pos = k2 + __popcll(mask & ((1ULL << lane) - 1ULL));
                if (pos < 256) edg[wid][pos] = (unsigned short)(val & 0xFFFFu);
            }
            k2 += __popcll(mask);
        }
        __threadfence_block();
        int nd = deg < 256 ? deg : 256;
        float m = -1e30f, l = 0.0f, acc = 0.0f;
        float dn = dd[n];
        for (int c0 = 0; c0 < nd; c0 += 64) {
            int j = c0 + lane;
            int sid = 0;
            float ev = -1e30f;
            if (j < nd) {
                sid = (int)edg[wid][j];
                float v = s[sid] + dn;
                ev = v > 0.0f ? v : 0.01f * v;
            }
            float cm = ev;
            #pragma unroll
            for (int o = 32; o > 0; o >>= 1)
                cm = fmaxf(cm, __shfl_xor(cm, o, 64));
            float np = (j < nd) ? __expf(ev - cm) : 0.0f;
            float cl = np;
            #pragma unroll
            for (int o = 32; o > 0; o >>= 1)
                cl += __shfl_xor(cl, o, 64);
            float cacc = 0.0f;
            int c = nd - c0; if (c > 64) c = 64;
            for (int k = 0; k < c; k += 16) {
                float fvv[16];
                #pragma unroll
                for (int u = 0; u < 16; u++) {
                    int sk = __builtin_amdgcn_readlane(sid, k + u);
                    fvv[u] = feature[sk * F + lane];
                }
                #pragma unroll
                for (int u = 0; u < 16; u++) {
                    float pk = __uint_as_float(
                        __builtin_amdgcn_readlane(__float_as_uint(np), k + u));
                    cacc = fmaf(pk, fvv[u], cacc);
                }
            }
            float mn = fmaxf(m, cm);
            float sc = __expf(m - mn);
            float sc2 = __expf(cm - mn);
            l = l * sc + cl * sc2;
            acc = acc * sc + cacc * sc2;
            m = mn;
        }
        out[n * F + lane] = acc / l;
    }
}

// F: MFMA projection, in place on d_out.
// out[n][o] = relu(sum_k x[n][k] * W[o][k] + b[o]),  x = [feature | hm].
// 16x16x32 bf16; per wave: 16 nodes x 64 outs. Each wave reads only the
// rows it writes (safe in-place). W staged in LDS bf16, stride 136.
__global__ __launch_bounds__(256) void k_proj(
        const float* __restrict__ feature,
        const float* __restrict__ lin_w, const float* __restrict__ lin_b,
        float* __restrict__ out) {
    __shared__ unsigned short Wl[64 * 136];
    int t = threadIdx.x;
    for (int i = t; i < 64 * 128; i += 256)
        Wl[(i >> 7) * 136 + (i & 127)] = f32_to_bf16_rne(lin_w[i]);
    __syncthreads();
    int wid = t >> 6, lane = t & 63;
    int wgl = blockIdx.x * 4 + wid;      // global wave id, 16 nodes each
    int n0 = wgl * 16;
    if (n0 >= N_NODES) return;           // 50000 = 16*3125 exact per wave
    int m = lane & 15, quad = lane >> 4;
    short8 afr[4];
    #pragma unroll
    for (int ks = 0; ks < 4; ks++) {
        int kb = ks * 32 + quad * 8;     // 8-aligned, never straddles 64
        const float* sp = (kb < 64) ? (feature + (size_t)(n0 + m) * F + kb)
                                    : (out + (size_t)(n0 + m) * F + (kb - 64));
        float4 x0 = ((const float4*)sp)[0];
        float4 x1 = ((const float4*)sp)[1];
        short8 a;
        a[0] = (short)f32_to_bf16_rne(x0.x);
        a[1] = (short)f32_to_bf16_rne(x0.y);
        a[2] = (short)f32_to_bf16_rne(x0.z);
        a[3] = (short)f32_to_bf16_rne(x0.w);
        a[4] = (short)f32_to_bf16_rne(x1.x);
        a[5] = (short)f32_to_bf16_rne(x1.y);
        a[6] = (short)f32_to_bf16_rne(x1.z);
        a[7] = (short)f32_to_bf16_rne(x1.w);
        afr[ks] = a;
    }
    #pragma unroll
    for (int nt = 0; nt < 4; nt++) {
        v4f acc = {0.0f, 0.0f, 0.0f, 0.0f};
        #pragma unroll
        for (int ks = 0; ks < 4; ks++) {
            int kb = ks * 32 + quad * 8;
            short8 b = *(const short8*)&Wl[(nt * 16 + m) * 136 + kb];
            acc = __builtin_amdgcn_mfma_f32_16x16x32_bf16(afr[ks], b, acc,
                                                          0, 0, 0);
        }
        int colo = nt * 16 + m;          // C/D: col = lane&15
        float bias = lin_b[colo];
        #pragma unroll
        for (int r = 0; r < 4; r++) {
            int row = quad * 4 + r;      // C/D: row = (lane>>4)*4 + reg
            float v = acc[r] + bias;
            out[(size_t)(n0 + row) * F + colo] = fmaxf(v, 0.0f);
        }
    }
}

extern "C" void kernel_launch(void* const* d_in, const int* in_sizes, int n_in,
                              void* d_out, int out_size, void* d_ws, size_t ws_size,
                              hipStream_t stream) {
    const float* feature = (const float*)d_in[0];
    const float* attn_w  = (const float*)d_in[1];
    const float* lin_w   = (const float*)d_in[2];
    const float* lin_b   = (const float*)d_in[3];
    const int*   src     = (const int*)d_in[4];
    const int*   dst     = (const int*)d_in[5];
    float* out = (float*)d_out;
    char* ws = (char*)d_ws;

    float*          s       = (float*)(ws);
    float*          dd      = (float*)(ws + 200000);
    int*            cnt     = (int*)  (ws + 400000);
    int*            bin_cnt = (int*)  (ws + 600000);
    int*            ovf_cnt = (int*)  (ws + 612544);
    unsigned*       ovf     = (unsigned*)(ws + 612608);
    unsigned short* bucket  = (unsigned short*)(ws + 616704);
    unsigned*       binned  = (unsigned*)(ws + 5516704);

    k_prep<<<(N_NODES * 64) / 256, 256, 0, stream>>>(
        feature, attn_w, s, dd, bin_cnt, ovf_cnt);
    k_bin<<<NTILE, 256, 0, stream>>>(src, dst, bin_cnt, binned);
    k_bucket<<<NBIN, 256, 0, stream>>>(
        binned, bin_cnt, cnt, bucket, ovf_cnt, ovf);
    k_aggregate<<<N_NODES / 8, 512, 0, stream>>>(
        bucket, cnt, s, dd, feature, out);
    k_cleanup<<<1, 256, 0, stream>>>(
        bucket, cnt, ovf_cnt, ovf, s, dd, feature, out);
    k_proj<<<(3125 + 3) / 4, 256, 0, stream>>>(feature, lin_w, lin_b, out);
}

// Round 9
// 147.968 us; speedup vs baseline: 5.7584x; 1.0843x over previous
//
#include <hip/hip_runtime.h>
#include <math.h>

#define N_NODES 50000
#define N_EDGES 1200000
#define F 64
#define CAP 49            // per-node bucket capacity (P(deg>49) ~ 2.5e-6/node)
#define OVF_MAX 1024
#define NBIN 196          // bins of 256 nodes (dst >> 8)
#define BSTR 16           // bin_cnt stride in ints (64B) - no line sharing
#define CAP_BIN 7680      // mean 6122 + ~20 sigma
#define TILE 8192         // edges per k_bin workgroup
#define NTILE ((N_EDGES + TILE - 1) / TILE)   // 147

typedef __attribute__((ext_vector_type(8))) short short8;
typedef __attribute__((ext_vector_type(4))) float v4f;

// ws layout (bytes; ws_size ~256MB so no aliasing needed):
//   s       [0,       200000)    float[50000]
//   dd      [200000,  400000)    float[50000]
//   cnt     [400000,  600000)    int[50000]      true degree (k_bucket)
//   bin_cnt [600000,  612544)    int[196*16]     strided counters
//   ovf_cnt [612544,  612608)    int + pad
//   ovf     [612608,  616704)    uint[1024]      (dst<<16)|src
//   bucket  [616704,  5516704)   ushort[50000*49]
//   binned  [5516704, 11537824)  uint[196*7680]
//   fb      [11537824,17937824)  ushort[50000*64] bf16 feature copy

__device__ __forceinline__ unsigned short f32_to_bf16_rne(float f) {
    unsigned u = __float_as_uint(f);
    return (unsigned short)((u + 0x7FFFu + ((u >> 16) & 1u)) >> 16);
}
__device__ __forceinline__ float bf16_to_f32(unsigned short u) {
    return __uint_as_float(((unsigned)u) << 16);
}

// A: per-node attention dots + bf16 copy + zero counters. One wave per node.
__global__ void k_prep(const float* __restrict__ feature,
                       const float* __restrict__ attn_w,
                       float* __restrict__ s, float* __restrict__ dd,
                       int* __restrict__ bin_cnt, int* __restrict__ ovf_cnt,
                       unsigned short* __restrict__ fb) {
    int gid = blockIdx.x * blockDim.x + threadIdx.x;
    if (gid < NBIN * BSTR) bin_cnt[gid] = 0;
    if (gid == NBIN * BSTR) *ovf_cnt = 0;
    int wave = gid >> 6;
    int lane = threadIdx.x & 63;
    if (wave >= N_NODES) return;
    float f = feature[wave * F + lane];
    fb[wave * F + lane] = f32_to_bf16_rne(f);
    float sv = f * attn_w[lane];
    float dv = f * attn_w[F + lane];
    #pragma unroll
    for (int o = 32; o > 0; o >>= 1) {
        sv += __shfl_down(sv, o, 64);
        dv += __shfl_down(dv, o, 64);
    }
    if (lane == 0) {
        s[wave] = sv;
        dd[wave] = dv;
    }
}

// B: LDS-staged binning. Per 8192-edge tile: count -> scan -> place in LDS,
// ONE global atomic per (tile,bin) to reserve, coalesced flush.
__global__ __launch_bounds__(256) void k_bin(
        const int* __restrict__ src, const int* __restrict__ dst,
        int* __restrict__ bin_cnt, unsigned* __restrict__ binned) {
    __shared__ unsigned ord[TILE];
    __shared__ int cnt_l[NBIN], off_l[NBIN], cur_l[NBIN], base_g[NBIN];
    __shared__ int buf[256];
    int t = threadIdx.x;
    int e0 = blockIdx.x * TILE;
    int ecnt = N_EDGES - e0; if (ecnt > TILE) ecnt = TILE;
    for (int i = t; i < NBIN; i += 256) cnt_l[i] = 0;
    __syncthreads();
    int n4 = ecnt >> 2;
    const int4* s4p = (const int4*)src + (e0 >> 2);
    const int4* d4p = (const int4*)dst + (e0 >> 2);
    for (int c = t; c < n4; c += 256) {
        int4 d4 = d4p[c];
        atomicAdd(&cnt_l[d4.x >> 8], 1);
        atomicAdd(&cnt_l[d4.y >> 8], 1);
        atomicAdd(&cnt_l[d4.z >> 8], 1);
        atomicAdd(&cnt_l[d4.w >> 8], 1);
    }
    __syncthreads();
    int v0 = (t < NBIN) ? cnt_l[t] : 0;
    buf[t] = v0;
    __syncthreads();
    #pragma unroll
    for (int d = 1; d < 256; d <<= 1) {
        int x = (t >= d) ? buf[t - d] : 0;
        __syncthreads();
        buf[t] += x;
        __syncthreads();
    }
    if (t < NBIN) {
        int off = buf[t] - v0;
        off_l[t] = off;
        cur_l[t] = off;
        base_g[t] = atomicAdd(&bin_cnt[t * BSTR], v0);  // bulk reserve
    }
    __syncthreads();
    for (int c = t; c < n4; c += 256) {
        int4 d4 = d4p[c];
        int4 s4 = s4p[c];
        int dv[4] = {d4.x, d4.y, d4.z, d4.w};
        int sv[4] = {s4.x, s4.y, s4.z, s4.w};
        #pragma unroll
        for (int u = 0; u < 4; u++) {
            int r = atomicAdd(&cur_l[dv[u] >> 8], 1);
            ord[r] = (((unsigned)dv[u]) << 16) | (unsigned)sv[u];
        }
    }
    __syncthreads();
    for (int i = t; i < ecnt; i += 256) {
        unsigned v = ord[i];
        int b = v >> 24;
        int pos = base_g[b] + (i - off_l[b]);
        if (pos < CAP_BIN) binned[(size_t)b * CAP_BIN + pos] = v;
    }
}

// C: one workgroup per bin — build per-node buckets in LDS, coalesced out.
__global__ __launch_bounds__(256) void k_bucket(
        const unsigned* __restrict__ binned, const int* __restrict__ bin_cnt,
        int* __restrict__ cnt, unsigned short* __restrict__ bucket,
        int* __restrict__ ovf_cnt, unsigned* __restrict__ ovf) {
    __shared__ int cnt_l[256];
    __shared__ __align__(16) unsigned short buck_l[256 * CAP];
    int bin = blockIdx.x;
    int t = threadIdx.x;
    int n0 = bin << 8;
    int nn = N_NODES - n0; if (nn > 256) nn = 256;
    cnt_l[t] = 0;
    __syncthreads();
    int E = bin_cnt[bin * BSTR];
    if (E > CAP_BIN) E = CAP_BIN;
    const unsigned* be = binned + (size_t)bin * CAP_BIN;
    for (int i = t; i < E; i += 256) {
        unsigned v = be[i];
        int local = (v >> 16) & 255;
        int sid = (int)(v & 0xFFFFu);
        int r = atomicAdd(&cnt_l[local], 1);
        if (r < CAP) {
            buck_l[local * CAP + r] = (unsigned short)sid;
        } else {
            int o = atomicAdd(ovf_cnt, 1);
            if (o < OVF_MAX)
                ovf[o] = ((unsigned)(n0 + local) << 16) | (unsigned)sid;
        }
    }
    __syncthreads();
    if (t < nn) cnt[n0 + t] = cnt_l[t];
    int nu4 = (nn * CAP * 2) >> 4;
    const uint4* bl4 = (const uint4*)buck_l;
    uint4* bg4 = (uint4*)(bucket + (size_t)n0 * CAP);
    for (int i = t; i < nu4; i += 256) bg4[i] = bl4[i];
}

// D: aggregation. 1 wave/node; softmax single-chunk (deg<=49). Gather bf16:
// 16-lane groups, 4 edges per load step, ushort4 (4 bf16) per lane; ALL
// loads for the node issued before any FMA (8 or 16 in flight).
__global__ __launch_bounds__(512) void k_aggregate(
        const unsigned short* __restrict__ bucket,
        const int* __restrict__ cnt,
        const float* __restrict__ s, const float* __restrict__ dd,
        const unsigned short* __restrict__ fb,
        float* __restrict__ out) {
    int t = threadIdx.x;
    int wid = t >> 6, lane = t & 63;
    int n = blockIdx.x * 8 + wid;        // grid exact: 6250*8 = 50000
    int deg = cnt[n];
    if (deg > CAP) return;               // k_cleanup writes these rows
    if (deg == 0) { out[n * F + lane] = 0.0f; return; }
    int si = 0;
    float ev = -1e30f;
    if (lane < deg) {
        si = (int)bucket[n * CAP + lane];
        float v = s[si] + dd[n];
        ev = v > 0.0f ? v : 0.01f * v;
    }
    float m = ev;
    #pragma unroll
    for (int o = 32; o > 0; o >>= 1)
        m = fmaxf(m, __shfl_xor(m, o, 64));
    float p = (lane < deg) ? __expf(ev - m) : 0.0f;
    float l = p;
    #pragma unroll
    for (int o = 32; o > 0; o >>= 1)
        l += __shfl_xor(l, o, 64);
    p *= __builtin_amdgcn_rcpf(l);

    int grp = lane >> 4;                 // edge-in-group-of-4
    int c16 = lane & 15;                 // ushort4 column within row
    const ushort4* f4 = (const ushort4*)fb;   // row stride = 16 ushort4
    ushort4 fv0[8], fv1[8];
    #pragma unroll
    for (int u = 0; u < 8; u++) {        // edges 0..31 (pad lanes: row 0, p=0)
        int sk = __shfl(si, u * 4 + grp, 64);
        fv0[u] = f4[sk * 16 + c16];
    }
    bool two = deg > 32;                 // wave-uniform
    if (two) {
        #pragma unroll
        for (int u = 0; u < 8; u++) {    // edges 32..63
            int sk = __shfl(si, 32 + u * 4 + grp, 64);
            fv1[u] = f4[sk * 16 + c16];
        }
    }
    float a0 = 0.0f, a1 = 0.0f, a2 = 0.0f, a3 = 0.0f;
    #pragma unroll
    for (int u = 0; u < 8; u++) {
        float pw = __shfl(p, u * 4 + grp, 64);
        a0 = fmaf(pw, bf16_to_f32(fv0[u].x), a0);
        a1 = fmaf(pw, bf16_to_f32(fv0[u].y), a1);
        a2 = fmaf(pw, bf16_to_f32(fv0[u].z), a2);
        a3 = fmaf(pw, bf16_to_f32(fv0[u].w), a3);
    }
    if (two) {
        #pragma unroll
        for (int u = 0; u < 8; u++) {
            float pw = __shfl(p, 32 + u * 4 + grp, 64);
            a0 = fmaf(pw, bf16_to_f32(fv1[u].x), a0);
            a1 = fmaf(pw, bf16_to_f32(fv1[u].y), a1);
            a2 = fmaf(pw, bf16_to_f32(fv1[u].z), a2);
            a3 = fmaf(pw, bf16_to_f32(fv1[u].w), a3);
        }
    }
    a0 += __shfl_xor(a0, 16, 64); a0 += __shfl_xor(a0, 32, 64);
    a1 += __shfl_xor(a1, 16, 64); a1 += __shfl_xor(a1, 32, 64);
    a2 += __shfl_xor(a2, 16, 64); a2 += __shfl_xor(a2, 32, 64);
    a3 += __shfl_xor(a3, 16, 64); a3 += __shfl_xor(a3, 32, 64);
    if (lane < 16) {
        v4f st = {a0, a1, a2, a3};
        ((v4f*)out)[n * 16 + c16] = st;
    }
}

// E: overflow cleanup — writes hm rows for nodes with deg > CAP (before proj).
__global__ __launch_bounds__(256) void k_cleanup(
        const unsigned short* __restrict__ bucket,
        const int* __restrict__ cnt,
        const int* __restrict__ ovf_cnt, const unsigned int* __restrict__ ovf,
        const float* __restrict__ s, const float* __restrict__ dd,
        const float* __restrict__ feature,
        float* __restrict__ out) {
    int M = *ovf_cnt;
    if (M > OVF_MAX) M = OVF_MAX;
    if (M == 0) return;
    __shared__ int list[128];
    __shared__ int nlist;
    __shared__ unsigned short edg[4][256];
    int t = threadIdx.x;
    if (t == 0) {
        nlist = 0;
        for (int i = 0; i < M; i++) {
            int d = (int)(ovf[i] >> 16);
            bool seen = false;
            for (int j = 0; j < nlist; j++) if (list[j] == d) seen = true;
            if (!seen && nlist < 128) list[nlist++] = d;
        }
    }
    __syncthreads();
    int wid = t >> 6, lane = t & 63;
    for (int idx = wid; idx < nlist; idx += 4) {
        int n = list[idx];
        int deg = cnt[n];
        if (lane < CAP) edg[wid][lane] = bucket[n * CAP + lane];
        int k2 = CAP;
        for (int base = 0; base < M; base += 64) {
            int i2 = base + lane;
            unsigned val = 0;
            bool mt = false;
            if (i2 < M) { val = ovf[i2]; mt = ((int)(val >> 16) == n); }
            unsigned long long mask = __ballot(mt);
            if (mt) {
                int pos = k2 + __popcll(mask & ((1ULL << lane) - 1ULL));
                if (pos < 256) edg[wid][pos] = (unsigned short)(val & 0xFFFFu);
            }
            k2 += __popcll(mask);
        }
        __threadfence_block();
        int nd = deg < 256 ? deg : 256;
        float m = -1e30f, l = 0.0f, acc = 0.0f;
        float dn = dd[n];
        for (int c0 = 0; c0 < nd; c0 += 64) {
            int j = c0 + lane;
            int sid = 0;
            float ev = -1e30f;
            if (j < nd) {
                sid = (int)edg[wid][j];
                float v = s[sid] + dn;
                ev = v > 0.0f ? v : 0.01f * v;
            }
            float cm = ev;
            #pragma unroll
            for (int o = 32; o > 0; o >>= 1)
                cm = fmaxf(cm, __shfl_xor(cm, o, 64));
            float np = (j < nd) ? __expf(ev - cm) : 0.0f;
            float cl = np;
            #pragma unroll
            for (int o = 32; o > 0; o >>= 1)
                cl += __shfl_xor(cl, o, 64);
            float cacc = 0.0f;
            int c = nd - c0; if (c > 64) c = 64;
            for (int k = 0; k < c; k += 16) {
                float fvv[16];
                #pragma unroll
                for (int u = 0; u < 16; u++) {
                    int sk = __builtin_amdgcn_readlane(sid, k + u);
                    fvv[u] = feature[sk * F + lane];
                }
                #pragma unroll
                for (int u = 0; u < 16; u++) {
                    float pk = __uint_as_float(
                        __builtin_amdgcn_readlane(__float_as_uint(np), k + u));
                    cacc = fmaf(pk, fvv[u], cacc);
                }
            }
            float mn = fmaxf(m, cm);
            float sc = __expf(m - mn);
            float sc2 = __expf(cm - mn);
            l = l * sc + cl * sc2;
            acc = acc * sc + cacc * sc2;
            m = mn;
        }
        out[n * F + lane] = acc / l;
    }
}

// F: MFMA projection, in place on d_out. x = [feature | hm]; feature
// fragments come straight from fb (bf16), hm fragments cvt from out.
__global__ __launch_bounds__(256) void k_proj(
        const unsigned short* __restrict__ fb,
        const float* __restrict__ lin_w, const float* __restrict__ lin_b,
        float* __restrict__ out) {
    __shared__ unsigned short Wl[64 * 136];
    int t = threadIdx.x;
    for (int i = t; i < 64 * 128; i += 256)
        Wl[(i >> 7) * 136 + (i & 127)] = f32_to_bf16_rne(lin_w[i]);
    __syncthreads();
    int wid = t >> 6, lane = t & 63;
    int wgl = blockIdx.x * 4 + wid;      // global wave id, 16 nodes each
    int n0 = wgl * 16;
    if (n0 >= N_NODES) return;
    int m = lane & 15, quad = lane >> 4;
    short8 afr[4];
    #pragma unroll
    for (int ks = 0; ks < 2; ks++) {     // k in [0,64): feature, from fb
        int kb = ks * 32 + quad * 8;
        afr[ks] = *(const short8*)&fb[(size_t)(n0 + m) * F + kb];
    }
    #pragma unroll
    for (int ks = 2; ks < 4; ks++) {     // k in [64,128): hm, cvt from out
        int kb = ks * 32 + quad * 8 - 64;
        const float* sp = out + (size_t)(n0 + m) * F + kb;
        float4 x0 = ((const float4*)sp)[0];
        float4 x1 = ((const float4*)sp)[1];
        short8 a;
        a[0] = (short)f32_to_bf16_rne(x0.x);
        a[1] = (short)f32_to_bf16_rne(x0.y);
        a[2] = (short)f32_to_bf16_rne(x0.z);
        a[3] = (short)f32_to_bf16_rne(x0.w);
        a[4] = (short)f32_to_bf16_rne(x1.x);
        a[5] = (short)f32_to_bf16_rne(x1.y);
        a[6] = (short)f32_to_bf16_rne(x1.z);
        a[7] = (short)f32_to_bf16_rne(x1.w);
        afr[ks] = a;
    }
    #pragma unroll
    for (int nt = 0; nt < 4; nt++) {
        v4f acc = {0.0f, 0.0f, 0.0f, 0.0f};
        #pragma unroll
        for (int ks = 0; ks < 4; ks++) {
            int kb = ks * 32 + quad * 8;
            short8 b = *(const short8*)&Wl[(nt * 16 + m) * 136 + kb];
            acc = __builtin_amdgcn_mfma_f32_16x16x32_bf16(afr[ks], b, acc,
                                                          0, 0, 0);
        }
        int colo = nt * 16 + m;          // C/D: col = lane&15
        float bias = lin_b[colo];
        #pragma unroll
        for (int r = 0; r < 4; r++) {
            int row = quad * 4 + r;      // C/D: row = (lane>>4)*4 + reg
            float v = acc[r] + bias;
            out[(size_t)(n0 + row) * F + colo] = fmaxf(v, 0.0f);
        }
    }
}

extern "C" void kernel_launch(void* const* d_in, const int* in_sizes, int n_in,
                              void* d_out, int out_size, void* d_ws, size_t ws_size,
                              hipStream_t stream) {
    const float* feature = (const float*)d_in[0];
    const float* attn_w  = (const float*)d_in[1];
    const float* lin_w   = (const float*)d_in[2];
    const float* lin_b   = (const float*)d_in[3];
    const int*   src     = (const int*)d_in[4];
    const int*   dst     = (const int*)d_in[5];
    float* out = (float*)d_out;
    char* ws = (char*)d_ws;

    float*          s       = (float*)(ws);
    float*          dd      = (float*)(ws + 200000);
    int*            cnt     = (int*)  (ws + 400000);
    int*            bin_cnt = (int*)  (ws + 600000);
    int*            ovf_cnt = (int*)  (ws + 612544);
    unsigned*       ovf     = (unsigned*)(ws + 612608);
    unsigned short* bucket  = (unsigned short*)(ws + 616704);
    unsigned*       binned  = (unsigned*)(ws + 5516704);
    unsigned short* fb      = (unsigned short*)(ws + 11537824);

    k_prep<<<(N_NODES * 64) / 256, 256, 0, stream>>>(
        feature, attn_w, s, dd, bin_cnt, ovf_cnt, fb);
    k_bin<<<NTILE, 256, 0, stream>>>(src, dst, bin_cnt, binned);
    k_bucket<<<NBIN, 256, 0, stream>>>(
        binned, bin_cnt, cnt, bucket, ovf_cnt, ovf);
    k_aggregate<<<N_NODES / 8, 512, 0, stream>>>(
        bucket, cnt, s, dd, fb, out);
    k_cleanup<<<1, 256, 0, stream>>>(
        bucket, cnt, ovf_cnt, ovf, s, dd, feature, out);
    k_proj<<<(3125 + 3) / 4, 256, 0, stream>>>(fb, lin_w, lin_b, out);
}

// Round 10
// 143.096 us; speedup vs baseline: 5.9544x; 1.0340x over previous
//
#include <hip/hip_runtime.h>
#include <math.h>

#define N_NODES 50000
#define N_EDGES 1200000
#define F 64
#define CAP 49            // per-node bucket capacity (P(deg>49) ~ 2.5e-6/node)
#define OVF_MAX 1024
#define NBIN 782          // bins of 64 nodes (dst >> 6)
#define BSTR 16           // bin_cnt stride in ints (64B) - no line sharing
#define CAP_BIN 2304      // mean 1536 + ~19.6 sigma
#define TILE 8192         // edges per k_bin workgroup
#define NTILE ((N_EDGES + TILE - 1) / TILE)   // 147

typedef __attribute__((ext_vector_type(8))) short short8;
typedef __attribute__((ext_vector_type(4))) float v4f;

// ws layout (bytes; ws_size ~256MB):
//   s       [0,        200000)    float[50000]
//   dd      [200000,   400000)    float[50000]
//   cnt     [400000,   600000)    int[50000]      true degree (k_fused)
//   bin_cnt [600000,   650048)    int[782*16]     strided counters
//   ovf_cnt [650048,   650112)    int + pad
//   ovf     [650112,   654208)    uint[1024]      (dst<<16)|src
//   bucket  [654208,   5554208)   ushort[50000*49] (only overflow rows written)
//   binned  [5554208,  12761120)  uint[782*2304]
//   fb      [12761120, 19161120)  ushort[50000*64] bf16 feature copy

__device__ __forceinline__ unsigned short f32_to_bf16_rne(float f) {
    unsigned u = __float_as_uint(f);
    return (unsigned short)((u + 0x7FFFu + ((u >> 16) & 1u)) >> 16);
}
__device__ __forceinline__ float bf16_to_f32(unsigned short u) {
    return __uint_as_float(((unsigned)u) << 16);
}

// A: per-node attention dots + bf16 copy + zero counters. One wave per node.
__global__ void k_prep(const float* __restrict__ feature,
                       const float* __restrict__ attn_w,
                       float* __restrict__ s, float* __restrict__ dd,
                       int* __restrict__ bin_cnt, int* __restrict__ ovf_cnt,
                       unsigned short* __restrict__ fb) {
    int gid = blockIdx.x * blockDim.x + threadIdx.x;
    if (gid < NBIN * BSTR) bin_cnt[gid] = 0;
    if (gid == NBIN * BSTR) *ovf_cnt = 0;
    int wave = gid >> 6;
    int lane = threadIdx.x & 63;
    if (wave >= N_NODES) return;
    float f = feature[wave * F + lane];
    fb[wave * F + lane] = f32_to_bf16_rne(f);
    float sv = f * attn_w[lane];
    float dv = f * attn_w[F + lane];
    #pragma unroll
    for (int o = 32; o > 0; o >>= 1) {
        sv += __shfl_down(sv, o, 64);
        dv += __shfl_down(dv, o, 64);
    }
    if (lane == 0) {
        s[wave] = sv;
        dd[wave] = dv;
    }
}

// B: LDS-staged binning (bins of 64 nodes). Per 8192-edge tile:
// count -> scan (4 bins/thread) -> place in LDS, one global atomic per
// (tile,bin) bulk reserve, coalesced-ish flush.
__global__ __launch_bounds__(256) void k_bin(
        const int* __restrict__ src, const int* __restrict__ dst,
        int* __restrict__ bin_cnt, unsigned* __restrict__ binned) {
    __shared__ unsigned ord[TILE];
    __shared__ int cnt_l[NBIN], off_l[NBIN], cur_l[NBIN], base_g[NBIN];
    __shared__ int buf[256];
    int t = threadIdx.x;
    int e0 = blockIdx.x * TILE;
    int ecnt = N_EDGES - e0; if (ecnt > TILE) ecnt = TILE;
    for (int i = t; i < NBIN; i += 256) cnt_l[i] = 0;
    __syncthreads();
    int n4 = ecnt >> 2;
    const int4* s4p = (const int4*)src + (e0 >> 2);
    const int4* d4p = (const int4*)dst + (e0 >> 2);
    for (int c = t; c < n4; c += 256) {
        int4 d4 = d4p[c];
        atomicAdd(&cnt_l[d4.x >> 6], 1);
        atomicAdd(&cnt_l[d4.y >> 6], 1);
        atomicAdd(&cnt_l[d4.z >> 6], 1);
        atomicAdd(&cnt_l[d4.w >> 6], 1);
    }
    __syncthreads();
    // exclusive scan over 782 bins: 4 bins/thread + 256-wide Hillis-Steele
    int c0[4];
    int sum = 0;
    #pragma unroll
    for (int j = 0; j < 4; j++) {
        int idx = t * 4 + j;
        c0[j] = (idx < NBIN) ? cnt_l[idx] : 0;
        sum += c0[j];
    }
    buf[t] = sum;
    __syncthreads();
    #pragma unroll
    for (int d = 1; d < 256; d <<= 1) {
        int x = (t >= d) ? buf[t - d] : 0;
        __syncthreads();
        buf[t] += x;
        __syncthreads();
    }
    int excl = buf[t] - sum;
    #pragma unroll
    for (int j = 0; j < 4; j++) {
        int idx = t * 4 + j;
        if (idx < NBIN) {
            off_l[idx] = excl;
            cur_l[idx] = excl;
            base_g[idx] = atomicAdd(&bin_cnt[idx * BSTR], c0[j]);  // reserve
        }
        excl += c0[j];
    }
    __syncthreads();
    for (int c = t; c < n4; c += 256) {
        int4 d4 = d4p[c];
        int4 s4 = s4p[c];
        int dv[4] = {d4.x, d4.y, d4.z, d4.w};
        int sv[4] = {s4.x, s4.y, s4.z, s4.w};
        #pragma unroll
        for (int u = 0; u < 4; u++) {
            int r = atomicAdd(&cur_l[dv[u] >> 6], 1);
            ord[r] = (((unsigned)dv[u]) << 16) | (unsigned)sv[u];
        }
    }
    __syncthreads();
    for (int i = t; i < ecnt; i += 256) {
        unsigned v = ord[i];
        int b = v >> 22;                 // dst>>6
        int pos = base_g[b] + (i - off_l[b]);
        if (pos < CAP_BIN) binned[(size_t)b * CAP_BIN + pos] = v;
    }
}

// C: mega-fused: bucket build (LDS) + softmax aggregation + MFMA projection.
// One 256-thread wg per 64-node bin (782 wgs). Wave w aggregates nodes
// w*16..w*16+15, parks hm in xl, then projects its own 16 nodes.
__global__ __launch_bounds__(256) void k_fused(
        const unsigned* __restrict__ binned, const int* __restrict__ bin_cnt,
        int* __restrict__ cnt, unsigned short* __restrict__ bucket,
        int* __restrict__ ovf_cnt, unsigned* __restrict__ ovf,
        const float* __restrict__ s, const float* __restrict__ dd,
        const unsigned short* __restrict__ fb,
        const float* __restrict__ lin_w, const float* __restrict__ lin_b,
        float* __restrict__ out) {
    __shared__ int cnt_l[64];
    __shared__ unsigned short buck_l[64 * CAP];   // 6272 B
    __shared__ unsigned short Wl[64 * 136];       // bf16 W, stride 136
    __shared__ float xl[4][16][64];               // per-wave hm rows
    int t = threadIdx.x;
    int wid = t >> 6, lane = t & 63;
    int bin = blockIdx.x;
    int n0 = bin << 6;
    int nn = N_NODES - n0; if (nn > 64) nn = 64;
    for (int i = t; i < 64 * 128; i += 256)
        Wl[(i >> 7) * 136 + (i & 127)] = f32_to_bf16_rne(lin_w[i]);
    if (t < 64) cnt_l[t] = 0;
    __syncthreads();
    // build buckets in LDS
    int E = bin_cnt[bin * BSTR];
    if (E > CAP_BIN) E = CAP_BIN;
    const unsigned* be = binned + (size_t)bin * CAP_BIN;
    for (int i = t; i < E; i += 256) {
        unsigned v = be[i];
        int local = (v >> 16) & 63;
        int sid = (int)(v & 0xFFFFu);
        int r = atomicAdd(&cnt_l[local], 1);
        if (r < CAP) {
            buck_l[local * CAP + r] = (unsigned short)sid;
        } else {
            int o = atomicAdd(ovf_cnt, 1);
            if (o < OVF_MAX)
                ovf[o] = ((unsigned)(n0 + local) << 16) | (unsigned)sid;
        }
    }
    __syncthreads();
    if (t < nn) {
        cnt[n0 + t] = cnt_l[t];
        if (cnt_l[t] > CAP) {            // rare: dump row for k_cleanup
            for (int k2 = 0; k2 < CAP; k2++)
                bucket[(size_t)(n0 + t) * CAP + k2] = buck_l[t * CAP + k2];
        }
    }
    __syncthreads();
    // aggregation: wave wid handles 16 nodes sequentially
    const ushort4* f4 = (const ushort4*)fb;
    for (int j = 0; j < 16; j++) {
        int local = wid * 16 + j;
        if (local >= nn) break;          // wave-uniform
        int deg = cnt_l[local];
        if (deg == 0 || deg > CAP) {     // empty or overflow: zero placeholder
            if (lane < 16) {
                v4f z = {0.0f, 0.0f, 0.0f, 0.0f};
                ((v4f*)&xl[wid][j][0])[lane] = z;
            }
            continue;
        }
        int si = 0;
        float ev = -1e30f;
        if (lane < deg) {
            si = (int)buck_l[local * CAP + lane];
            float v = s[si] + dd[n0 + local];
            ev = v > 0.0f ? v : 0.01f * v;
        }
        float m = ev;
        #pragma unroll
        for (int o = 32; o > 0; o >>= 1)
            m = fmaxf(m, __shfl_xor(m, o, 64));
        float p = (lane < deg) ? __expf(ev - m) : 0.0f;
        float l = p;
        #pragma unroll
        for (int o = 32; o > 0; o >>= 1)
            l += __shfl_xor(l, o, 64);
        p *= __builtin_amdgcn_rcpf(l);
        int grp = lane >> 4;
        int c16 = lane & 15;
        ushort4 fv0[8], fv1[8];
        #pragma unroll
        for (int u = 0; u < 8; u++) {    // edges 0..31 (pad lanes: row 0, p=0)
            int sk = __shfl(si, u * 4 + grp, 64);
            fv0[u] = f4[sk * 16 + c16];
        }
        bool two = deg > 32;             // wave-uniform
        if (two) {
            #pragma unroll
            for (int u = 0; u < 8; u++) {
                int sk = __shfl(si, 32 + u * 4 + grp, 64);
                fv1[u] = f4[sk * 16 + c16];
            }
        }
        float a0 = 0.0f, a1 = 0.0f, a2 = 0.0f, a3 = 0.0f;
        #pragma unroll
        for (int u = 0; u < 8; u++) {
            float pw = __shfl(p, u * 4 + grp, 64);
            a0 = fmaf(pw, bf16_to_f32(fv0[u].x), a0);
            a1 = fmaf(pw, bf16_to_f32(fv0[u].y), a1);
            a2 = fmaf(pw, bf16_to_f32(fv0[u].z), a2);
            a3 = fmaf(pw, bf16_to_f32(fv0[u].w), a3);
        }
        if (two) {
            #pragma unroll
            for (int u = 0; u < 8; u++) {
                float pw = __shfl(p, 32 + u * 4 + grp, 64);
                a0 = fmaf(pw, bf16_to_f32(fv1[u].x), a0);
                a1 = fmaf(pw, bf16_to_f32(fv1[u].y), a1);
                a2 = fmaf(pw, bf16_to_f32(fv1[u].z), a2);
                a3 = fmaf(pw, bf16_to_f32(fv1[u].w), a3);
            }
        }
        a0 += __shfl_xor(a0, 16, 64); a0 += __shfl_xor(a0, 32, 64);
        a1 += __shfl_xor(a1, 16, 64); a1 += __shfl_xor(a1, 32, 64);
        a2 += __shfl_xor(a2, 16, 64); a2 += __shfl_xor(a2, 32, 64);
        a3 += __shfl_xor(a3, 16, 64); a3 += __shfl_xor(a3, 32, 64);
        if (lane < 16) {
            v4f st = {a0, a1, a2, a3};
            ((v4f*)&xl[wid][j][0])[c16] = st;
        }
    }
    // projection: wave projects its own 16 nodes (xl is wave-private; the
    // compiler orders LDS via lgkmcnt). x = [fb row | xl row].
    int n0w = n0 + wid * 16;
    if (n0w >= N_NODES) return;          // wave-uniform (only last bin)
    int m = lane & 15, quad = lane >> 4;
    short8 afr[4];
    #pragma unroll
    for (int ks = 0; ks < 2; ks++) {     // k in [0,64): feature from fb
        int kb = ks * 32 + quad * 8;
        afr[ks] = *(const short8*)&fb[(size_t)(n0w + m) * F + kb];
    }
    #pragma unroll
    for (int ks = 2; ks < 4; ks++) {     // k in [64,128): hm from xl
        int kb = ks * 32 + quad * 8 - 64;
        const float* sp = &xl[wid][m][kb];
        float4 x0 = ((const float4*)sp)[0];
        float4 x1 = ((const float4*)sp)[1];
        short8 a;
        a[0] = (short)f32_to_bf16_rne(x0.x);
        a[1] = (short)f32_to_bf16_rne(x0.y);
        a[2] = (short)f32_to_bf16_rne(x0.z);
        a[3] = (short)f32_to_bf16_rne(x0.w);
        a[4] = (short)f32_to_bf16_rne(x1.x);
        a[5] = (short)f32_to_bf16_rne(x1.y);
        a[6] = (short)f32_to_bf16_rne(x1.z);
        a[7] = (short)f32_to_bf16_rne(x1.w);
        afr[ks] = a;
    }
    #pragma unroll
    for (int nt = 0; nt < 4; nt++) {
        v4f acc = {0.0f, 0.0f, 0.0f, 0.0f};
        #pragma unroll
        for (int ks = 0; ks < 4; ks++) {
            int kb = ks * 32 + quad * 8;
            short8 b = *(const short8*)&Wl[(nt * 16 + m) * 136 + kb];
            acc = __builtin_amdgcn_mfma_f32_16x16x32_bf16(afr[ks], b, acc,
                                                          0, 0, 0);
        }
        int colo = nt * 16 + m;          // C/D: col = lane&15
        float bias = lin_b[colo];
        #pragma unroll
        for (int r = 0; r < 4; r++) {
            int row = quad * 4 + r;      // C/D: row = (lane>>4)*4 + reg
            float v = acc[r] + bias;
            out[(size_t)(n0w + row) * F + colo] = fmaxf(v, 0.0f);
        }
    }
}

// D: overflow cleanup — recompute hm AND projection for deg>CAP nodes.
__global__ __launch_bounds__(256) void k_cleanup(
        const unsigned short* __restrict__ bucket,
        const int* __restrict__ cnt,
        const int* __restrict__ ovf_cnt, const unsigned int* __restrict__ ovf,
        const float* __restrict__ s, const float* __restrict__ dd,
        const float* __restrict__ feature,
        const float* __restrict__ lin_w, const float* __restrict__ lin_b,
        float* __restrict__ out) {
    int M = *ovf_cnt;
    if (M > OVF_MAX) M = OVF_MAX;
    if (M == 0) return;                  // uniform, before any barrier
    __shared__ float Wl[64 * 129];
    __shared__ int list[128];
    __shared__ int nlist;
    __shared__ unsigned short edg[4][256];
    __shared__ float xc[4][128];
    int t = threadIdx.x;
    for (int i = t; i < 64 * 128; i += 256)
        Wl[(i >> 7) * 129 + (i & 127)] = lin_w[i];
    if (t == 0) {
        nlist = 0;
        for (int i = 0; i < M; i++) {
            int d = (int)(ovf[i] >> 16);
            bool seen = false;
            for (int j = 0; j < nlist; j++) if (list[j] == d) seen = true;
            if (!seen && nlist < 128) list[nlist++] = d;
        }
    }
    __syncthreads();
    int wid = t >> 6, lane = t & 63;
    for (int idx = wid; idx < nlist; idx += 4) {
        int n = list[idx];
        int deg = cnt[n];
        if (lane < CAP) edg[wid][lane] = bucket[n * CAP + lane];
        int k2 = CAP;
        for (int base = 0; base < M; base += 64) {
            int i2 = base + lane;
            unsigned val = 0;
            bool mt = false;
            if (i2 < M) { val = ovf[i2]; mt = ((int)(val >> 16) == n); }
            unsigned long long mask = __ballot(mt);
            if (mt) {
                int pos = k2 + __popcll(mask & ((1ULL << lane) - 1ULL));
                if (pos < 256) edg[wid][pos] = (unsigned short)(val & 0xFFFFu);
            }
            k2 += __popcll(mask);
        }
        __threadfence_block();
        int nd = deg < 256 ? deg : 256;
        float m = -1e30f, l = 0.0f, acc = 0.0f;
        float dn = dd[n];
        for (int c0 = 0; c0 < nd; c0 += 64) {
            int j = c0 + lane;
            int sid = 0;
            float ev = -1e30f;
            if (j < nd) {
                sid = (int)edg[wid][j];
                float v = s[sid] + dn;
                ev = v > 0.0f ? v : 0.01f * v;
            }
            float cm = ev;
            #pragma unroll
            for (int o = 32; o > 0; o >>= 1)
                cm = fmaxf(cm, __shfl_xor(cm, o, 64));
            float np = (j < nd) ? __expf(ev - cm) : 0.0f;
            float cl = np;
            #pragma unroll
            for (int o = 32; o > 0; o >>= 1)
                cl += __shfl_xor(cl, o, 64);
            float cacc = 0.0f;
            int c = nd - c0; if (c > 64) c = 64;
            for (int k = 0; k < c; k += 16) {
                float fvv[16];
                #pragma unroll
                for (int u = 0; u < 16; u++) {
                    int sk = __builtin_amdgcn_readlane(sid, k + u);
                    fvv[u] = feature[sk * F + lane];
                }
                #pragma unroll
                for (int u = 0; u < 16; u++) {
                    float pk = __uint_as_float(
                        __builtin_amdgcn_readlane(__float_as_uint(np), k + u));
                    cacc = fmaf(pk, fvv[u], cacc);
                }
            }
            float mn = fmaxf(m, cm);
            float sc = __expf(m - mn);
            float sc2 = __expf(cm - mn);
            l = l * sc + cl * sc2;
            acc = acc * sc + cacc * sc2;
            m = mn;
        }
        float hm = acc / l;
        xc[wid][lane] = feature[n * F + lane];
        xc[wid][64 + lane] = hm;
        __threadfence_block();
        float oa = lin_b[lane];
        #pragma unroll
        for (int k = 0; k < 128; k++)
            oa += xc[wid][k] * Wl[lane * 129 + k];
        out[n * F + lane] = fmaxf(oa, 0.0f);
    }
}

extern "C" void kernel_launch(void* const* d_in, const int* in_sizes, int n_in,
                              void* d_out, int out_size, void* d_ws, size_t ws_size,
                              hipStream_t stream) {
    const float* feature = (const float*)d_in[0];
    const float* attn_w  = (const float*)d_in[1];
    const float* lin_w   = (const float*)d_in[2];
    const float* lin_b   = (const float*)d_in[3];
    const int*   src     = (const int*)d_in[4];
    const int*   dst     = (const int*)d_in[5];
    float* out = (float*)d_out;
    char* ws = (char*)d_ws;

    float*          s       = (float*)(ws);
    float*          dd      = (float*)(ws + 200000);
    int*            cnt     = (int*)  (ws + 400000);
    int*            bin_cnt = (int*)  (ws + 600000);
    int*            ovf_cnt = (int*)  (ws + 650048);
    unsigned*       ovf     = (unsigned*)(ws + 650112);
    unsigned short* bucket  = (unsigned short*)(ws + 654208);
    unsigned*       binned  = (unsigned*)(ws + 5554208);
    unsigned short* fb      = (unsigned short*)(ws + 12761120);

    k_prep<<<(N_NODES * 64) / 256, 256, 0, stream>>>(
        feature, attn_w, s, dd, bin_cnt, ovf_cnt, fb);
    k_bin<<<NTILE, 256, 0, stream>>>(src, dst, bin_cnt, binned);
    k_fused<<<NBIN, 256, 0, stream>>>(
        binned, bin_cnt, cnt, bucket, ovf_cnt, ovf, s, dd, fb,
        lin_w, lin_b, out);
    k_cleanup<<<1, 256, 0, stream>>>(
        bucket, cnt, ovf_cnt, ovf, s, dd, feature, lin_w, lin_b, out);
}

// Round 11
// 141.877 us; speedup vs baseline: 6.0056x; 1.0086x over previous
//
#include <hip/hip_runtime.h>
#include <math.h>

#define N_NODES 50000
#define N_EDGES 1200000
#define F 64
#define CAP 49            // per-node bucket capacity (P(deg>49) ~ 2.5e-6/node)
#define OVF_MAX 1024
#define NBIN 782          // bins of 64 nodes (dst >> 6)
#define BSTR 16           // bin_cnt stride in ints (64B) - no line sharing
#define CAP_BIN 2304      // mean 1536 + ~19.6 sigma
#define TILE 8192         // edges per k_bin workgroup
#define NTILE ((N_EDGES + TILE - 1) / TILE)   // 147
#define XSTR 72           // xl row stride in ushorts (16B-aligned, low-conflict)

typedef __attribute__((ext_vector_type(8))) short short8;
typedef __attribute__((ext_vector_type(4))) float v4f;

// ws layout (bytes; ws_size ~256MB):
//   s       [0,        200000)    float[50000]
//   dd      [200000,   400000)    float[50000]
//   cnt     [400000,   600000)    int[50000]      true degree (k_fused)
//   bin_cnt [600000,   650048)    int[782*16]     strided counters
//   ovf_cnt [650048,   650112)    int + pad
//   ovf     [650112,   654208)    uint[1024]      (dst<<16)|src
//   bucket  [654208,   5554208)   ushort[50000*49] (only overflow rows written)
//   binned  [5554208,  12761120)  uint[782*2304]
//   fb      [12761120, 19161120)  ushort[50000*64] bf16 feature copy

__device__ __forceinline__ unsigned short f32_to_bf16_rne(float f) {
    unsigned u = __float_as_uint(f);
    return (unsigned short)((u + 0x7FFFu + ((u >> 16) & 1u)) >> 16);
}
__device__ __forceinline__ float bf16_to_f32(unsigned short u) {
    return __uint_as_float(((unsigned)u) << 16);
}

// A: per-node attention dots + bf16 copy + zero counters. One wave per node.
__global__ void k_prep(const float* __restrict__ feature,
                       const float* __restrict__ attn_w,
                       float* __restrict__ s, float* __restrict__ dd,
                       int* __restrict__ bin_cnt, int* __restrict__ ovf_cnt,
                       unsigned short* __restrict__ fb) {
    int gid = blockIdx.x * blockDim.x + threadIdx.x;
    if (gid < NBIN * BSTR) bin_cnt[gid] = 0;
    if (gid == NBIN * BSTR) *ovf_cnt = 0;
    int wave = gid >> 6;
    int lane = threadIdx.x & 63;
    if (wave >= N_NODES) return;
    float f = feature[wave * F + lane];
    fb[wave * F + lane] = f32_to_bf16_rne(f);
    float sv = f * attn_w[lane];
    float dv = f * attn_w[F + lane];
    #pragma unroll
    for (int o = 32; o > 0; o >>= 1) {
        sv += __shfl_down(sv, o, 64);
        dv += __shfl_down(dv, o, 64);
    }
    if (lane == 0) {
        s[wave] = sv;
        dd[wave] = dv;
    }
}

// B: LDS-staged binning (bins of 64 nodes). Edges register-cached between
// passes (32/thread max). One global atomic per (tile,bin) bulk reserve.
__global__ __launch_bounds__(256) void k_bin(
        const int* __restrict__ src, const int* __restrict__ dst,
        int* __restrict__ bin_cnt, unsigned* __restrict__ binned) {
    __shared__ unsigned ord[TILE];
    __shared__ int cnt_l[NBIN], off_l[NBIN], cur_l[NBIN], base_g[NBIN];
    __shared__ int buf[256];
    int t = threadIdx.x;
    int e0 = blockIdx.x * TILE;
    int ecnt = N_EDGES - e0; if (ecnt > TILE) ecnt = TILE;
    for (int i = t; i < NBIN; i += 256) cnt_l[i] = 0;
    __syncthreads();
    int n4 = ecnt >> 2;
    const int4* s4p = (const int4*)src + (e0 >> 2);
    const int4* d4p = (const int4*)dst + (e0 >> 2);
    // pass 1: load, pack into registers, count
    unsigned pk[32];
    int ng = 0;                          // int4 groups this thread owns
    #pragma unroll
    for (int k = 0; k < 8; k++) {
        int c = t + k * 256;
        if (c < n4) {
            int4 d4 = d4p[c];
            int4 s4 = s4p[c];
            pk[4 * k + 0] = (((unsigned)d4.x) << 16) | (unsigned)s4.x;
            pk[4 * k + 1] = (((unsigned)d4.y) << 16) | (unsigned)s4.y;
            pk[4 * k + 2] = (((unsigned)d4.z) << 16) | (unsigned)s4.z;
            pk[4 * k + 3] = (((unsigned)d4.w) << 16) | (unsigned)s4.w;
            atomicAdd(&cnt_l[pk[4 * k + 0] >> 22], 1);
            atomicAdd(&cnt_l[pk[4 * k + 1] >> 22], 1);
            atomicAdd(&cnt_l[pk[4 * k + 2] >> 22], 1);
            atomicAdd(&cnt_l[pk[4 * k + 3] >> 22], 1);
            ng = k + 1;
        }
    }
    __syncthreads();
    // exclusive scan over 782 bins: 4 bins/thread + 256-wide Hillis-Steele
    int c0[4];
    int sum = 0;
    #pragma unroll
    for (int j = 0; j < 4; j++) {
        int idx = t * 4 + j;
        c0[j] = (idx < NBIN) ? cnt_l[idx] : 0;
        sum += c0[j];
    }
    buf[t] = sum;
    __syncthreads();
    #pragma unroll
    for (int d = 1; d < 256; d <<= 1) {
        int x = (t >= d) ? buf[t - d] : 0;
        __syncthreads();
        buf[t] += x;
        __syncthreads();
    }
    int excl = buf[t] - sum;
    #pragma unroll
    for (int j = 0; j < 4; j++) {
        int idx = t * 4 + j;
        if (idx < NBIN) {
            off_l[idx] = excl;
            cur_l[idx] = excl;
            base_g[idx] = atomicAdd(&bin_cnt[idx * BSTR], c0[j]);  // reserve
        }
        excl += c0[j];
    }
    __syncthreads();
    // pass 2: place from registers into LDS in bin order
    for (int k = 0; k < ng; k++) {
        #pragma unroll
        for (int u = 0; u < 4; u++) {
            unsigned v = pk[4 * k + u];
            int r = atomicAdd(&cur_l[v >> 22], 1);
            ord[r] = v;
        }
    }
    __syncthreads();
    for (int i = t; i < ecnt; i += 256) {
        unsigned v = ord[i];
        int b = v >> 22;                 // dst>>6
        int pos = base_g[b] + (i - off_l[b]);
        if (pos < CAP_BIN) binned[(size_t)b * CAP_BIN + pos] = v;
    }
}

// C: mega-fused: bucket build (LDS) + softmax aggregation + MFMA projection.
// One 256-thread wg per 64-node bin (782 wgs). Wave w aggregates nodes
// w*16..w*16+15, parks hm (bf16) in xl, then projects its own 16 nodes.
__global__ __launch_bounds__(256, 4) void k_fused(
        const unsigned* __restrict__ binned, const int* __restrict__ bin_cnt,
        int* __restrict__ cnt, unsigned short* __restrict__ bucket,
        int* __restrict__ ovf_cnt, unsigned* __restrict__ ovf,
        const float* __restrict__ s, const float* __restrict__ dd,
        const unsigned short* __restrict__ fb,
        const float* __restrict__ lin_w, const float* __restrict__ lin_b,
        float* __restrict__ out) {
    __shared__ int cnt_l[64];
    __shared__ unsigned short buck_l[64 * CAP];         // 6272 B
    __shared__ unsigned short Wl[64 * 136];             // bf16 W, 17408 B
    __shared__ __align__(16) unsigned short xl[4][16][XSTR];  // bf16 hm, 9216 B
    int t = threadIdx.x;
    int wid = t >> 6, lane = t & 63;
    int bin = blockIdx.x;
    int n0 = bin << 6;
    int nn = N_NODES - n0; if (nn > 64) nn = 64;
    for (int i = t; i < 64 * 128; i += 256)
        Wl[(i >> 7) * 136 + (i & 127)] = f32_to_bf16_rne(lin_w[i]);
    if (t < 64) cnt_l[t] = 0;
    __syncthreads();
    // build buckets in LDS
    int E = bin_cnt[bin * BSTR];
    if (E > CAP_BIN) E = CAP_BIN;
    const unsigned* be = binned + (size_t)bin * CAP_BIN;
    for (int i = t; i < E; i += 256) {
        unsigned v = be[i];
        int local = (v >> 16) & 63;
        int sid = (int)(v & 0xFFFFu);
        int r = atomicAdd(&cnt_l[local], 1);
        if (r < CAP) {
            buck_l[local * CAP + r] = (unsigned short)sid;
        } else {
            int o = atomicAdd(ovf_cnt, 1);
            if (o < OVF_MAX)
                ovf[o] = ((unsigned)(n0 + local) << 16) | (unsigned)sid;
        }
    }
    __syncthreads();
    if (t < nn) {
        cnt[n0 + t] = cnt_l[t];
        if (cnt_l[t] > CAP) {            // rare: dump row for k_cleanup
            for (int k2 = 0; k2 < CAP; k2++)
                bucket[(size_t)(n0 + t) * CAP + k2] = buck_l[t * CAP + k2];
        }
    }
    __syncthreads();
    // aggregation: wave wid handles 16 nodes sequentially
    const ushort4* f4 = (const ushort4*)fb;
    for (int j = 0; j < 16; j++) {
        int local = wid * 16 + j;
        if (local >= nn) break;          // wave-uniform
        int deg = cnt_l[local];
        if (deg == 0 || deg > CAP) {     // empty or overflow: zero placeholder
            if (lane < 16) {
                ushort4 z = {0, 0, 0, 0};
                *(ushort4*)&xl[wid][j][lane * 4] = z;
            }
            continue;
        }
        int si = 0;
        float ev = -1e30f;
        if (lane < deg) {
            si = (int)buck_l[local * CAP + lane];
            float v = s[si] + dd[n0 + local];
            ev = v > 0.0f ? v : 0.01f * v;
        }
        float m = ev;
        #pragma unroll
        for (int o = 32; o > 0; o >>= 1)
            m = fmaxf(m, __shfl_xor(m, o, 64));
        float p = (lane < deg) ? __expf(ev - m) : 0.0f;
        float l = p;
        #pragma unroll
        for (int o = 32; o > 0; o >>= 1)
            l += __shfl_xor(l, o, 64);
        p *= __builtin_amdgcn_rcpf(l);
        int grp = lane >> 4;
        int c16 = lane & 15;
        ushort4 fv0[8], fv1[8];
        #pragma unroll
        for (int u = 0; u < 8; u++) {    // edges 0..31 (pad lanes: row 0, p=0)
            int sk = __shfl(si, u * 4 + grp, 64);
            fv0[u] = f4[sk * 16 + c16];
        }
        bool two = deg > 32;             // wave-uniform
        if (two) {
            #pragma unroll
            for (int u = 0; u < 8; u++) {
                int sk = __shfl(si, 32 + u * 4 + grp, 64);
                fv1[u] = f4[sk * 16 + c16];
            }
        }
        float a0 = 0.0f, a1 = 0.0f, a2 = 0.0f, a3 = 0.0f;
        #pragma unroll
        for (int u = 0; u < 8; u++) {
            float pw = __shfl(p, u * 4 + grp, 64);
            a0 = fmaf(pw, bf16_to_f32(fv0[u].x), a0);
            a1 = fmaf(pw, bf16_to_f32(fv0[u].y), a1);
            a2 = fmaf(pw, bf16_to_f32(fv0[u].z), a2);
            a3 = fmaf(pw, bf16_to_f32(fv0[u].w), a3);
        }
        if (two) {
            #pragma unroll
            for (int u = 0; u < 8; u++) {
                float pw = __shfl(p, 32 + u * 4 + grp, 64);
                a0 = fmaf(pw, bf16_to_f32(fv1[u].x), a0);
                a1 = fmaf(pw, bf16_to_f32(fv1[u].y), a1);
                a2 = fmaf(pw, bf16_to_f32(fv1[u].z), a2);
                a3 = fmaf(pw, bf16_to_f32(fv1[u].w), a3);
            }
        }
        a0 += __shfl_xor(a0, 16, 64); a0 += __shfl_xor(a0, 32, 64);
        a1 += __shfl_xor(a1, 16, 64); a1 += __shfl_xor(a1, 32, 64);
        a2 += __shfl_xor(a2, 16, 64); a2 += __shfl_xor(a2, 32, 64);
        a3 += __shfl_xor(a3, 16, 64); a3 += __shfl_xor(a3, 32, 64);
        if (lane < 16) {
            ushort4 st;
            st.x = f32_to_bf16_rne(a0);
            st.y = f32_to_bf16_rne(a1);
            st.z = f32_to_bf16_rne(a2);
            st.w = f32_to_bf16_rne(a3);
            *(ushort4*)&xl[wid][j][c16 * 4] = st;
        }
    }
    // projection: wave projects its own 16 nodes (xl wave-private; compiler
    // orders LDS via lgkmcnt). x = [fb row | xl row].
    int n0w = n0 + wid * 16;
    if (n0w >= N_NODES) return;          // wave-uniform (only last bin)
    int m = lane & 15, quad = lane >> 4;
    short8 afr[4];
    #pragma unroll
    for (int ks = 0; ks < 2; ks++) {     // k in [0,64): feature from fb
        int kb = ks * 32 + quad * 8;
        afr[ks] = *(const short8*)&fb[(size_t)(n0w + m) * F + kb];
    }
    #pragma unroll
    for (int ks = 2; ks < 4; ks++) {     // k in [64,128): hm from xl (bf16)
        int kb = (ks - 2) * 32 + quad * 8;
        afr[ks] = *(const short8*)&xl[wid][m][kb];
    }
    #pragma unroll
    for (int nt = 0; nt < 4; nt++) {
        v4f acc = {0.0f, 0.0f, 0.0f, 0.0f};
        #pragma unroll
        for (int ks = 0; ks < 4; ks++) {
            int kb = ks * 32 + quad * 8;
            short8 b = *(const short8*)&Wl[(nt * 16 + m) * 136 + kb];
            acc = __builtin_amdgcn_mfma_f32_16x16x32_bf16(afr[ks], b, acc,
                                                          0, 0, 0);
        }
        int colo = nt * 16 + m;          // C/D: col = lane&15
        float bias = lin_b[colo];
        #pragma unroll
        for (int r = 0; r < 4; r++) {
            int row = quad * 4 + r;      // C/D: row = (lane>>4)*4 + reg
            float v = acc[r] + bias;
            out[(size_t)(n0w + row) * F + colo] = fmaxf(v, 0.0f);
        }
    }
}

// D: overflow cleanup — recompute hm AND projection for deg>CAP nodes.
__global__ __launch_bounds__(256) void k_cleanup(
        const unsigned short* __restrict__ bucket,
        const int* __restrict__ cnt,
        const int* __restrict__ ovf_cnt, const unsigned int* __restrict__ ovf,
        const float* __restrict__ s, const float* __restrict__ dd,
        const float* __restrict__ feature,
        const float* __restrict__ lin_w, const float* __restrict__ lin_b,
        float* __restrict__ out) {
    int M = *ovf_cnt;
    if (M > OVF_MAX) M = OVF_MAX;
    if (M == 0) return;                  // uniform, before any barrier
    __shared__ float Wl[64 * 129];
    __shared__ int list[128];
    __shared__ int nlist;
    __shared__ unsigned short edg[4][256];
    __shared__ float xc[4][128];
    int t = threadIdx.x;
    for (int i = t; i < 64 * 128; i += 256)
        Wl[(i >> 7) * 129 + (i & 127)] = lin_w[i];
    if (t == 0) {
        nlist = 0;
        for (int i = 0; i < M; i++) {
            int d = (int)(ovf[i] >> 16);
            bool seen = false;
            for (int j = 0; j < nlist; j++) if (list[j] == d) seen = true;
            if (!seen && nlist < 128) list[nlist++] = d;
        }
    }
    __syncthreads();
    int wid = t >> 6, lane = t & 63;
    for (int idx = wid; idx < nlist; idx += 4) {
        int n = list[idx];
        int deg = cnt[n];
        if (lane < CAP) edg[wid][lane] = bucket[n * CAP + lane];
        int k2 = CAP;
        for (int base = 0; base < M; base += 64) {
            int i2 = base + lane;
            unsigned val = 0;
            bool mt = false;
            if (i2 < M) { val = ovf[i2]; mt = ((int)(val >> 16) == n); }
            unsigned long long mask = __ballot(mt);
            if (mt) {
                int pos = k2 + __popcll(mask & ((1ULL << lane) - 1ULL));
                if (pos < 256) edg[wid][pos] = (unsigned short)(val & 0xFFFFu);
            }
            k2 += __popcll(mask);
        }
        __threadfence_block();
        int nd = deg < 256 ? deg : 256;
        float m = -1e30f, l = 0.0f, acc = 0.0f;
        float dn = dd[n];
        for (int c0 = 0; c0 < nd; c0 += 64) {
            int j = c0 + lane;
            int sid = 0;
            float ev = -1e30f;
            if (j < nd) {
                sid = (int)edg[wid][j];
                float v = s[sid] + dn;
                ev = v > 0.0f ? v : 0.01f * v;
            }
            float cm = ev;
            #pragma unroll
            for (int o = 32; o > 0; o >>= 1)
                cm = fmaxf(cm, __shfl_xor(cm, o, 64));
            float np = (j < nd) ? __expf(ev - cm) : 0.0f;
            float cl = np;
            #pragma unroll
            for (int o = 32; o > 0; o >>= 1)
                cl += __shfl_xor(cl, o, 64);
            float cacc = 0.0f;
            int c = nd - c0; if (c > 64) c = 64;
            for (int k = 0; k < c; k += 16) {
                float fvv[16];
                #pragma unroll
                for (int u = 0; u < 16; u++) {
                    int sk = __builtin_amdgcn_readlane(sid, k + u);
                    fvv[u] = feature[sk * F + lane];
                }
                #pragma unroll
                for (int u = 0; u < 16; u++) {
                    float pk = __uint_as_float(
                        __builtin_amdgcn_readlane(__float_as_uint(np), k + u));
                    cacc = fmaf(pk, fvv[u], cacc);
                }
            }
            float mn = fmaxf(m, cm);
            float sc = __expf(m - mn);
            float sc2 = __expf(cm - mn);
            l = l * sc + cl * sc2;
            acc = acc * sc + cacc * sc2;
            m = mn;
        }
        float hm = acc / l;
        xc[wid][lane] = feature[n * F + lane];
        xc[wid][64 + lane] = hm;
        __threadfence_block();
        float oa = lin_b[lane];
        #pragma unroll
        for (int k = 0; k < 128; k++)
            oa += xc[wid][k] * Wl[lane * 129 + k];
        out[n * F + lane] = fmaxf(oa, 0.0f);
    }
}

extern "C" void kernel_launch(void* const* d_in, const int* in_sizes, int n_in,
                              void* d_out, int out_size, void* d_ws, size_t ws_size,
                              hipStream_t stream) {
    const float* feature = (const float*)d_in[0];
    const float* attn_w  = (const float*)d_in[1];
    const float* lin_w   = (const float*)d_in[2];
    const float* lin_b   = (const float*)d_in[3];
    const int*   src     = (const int*)d_in[4];
    const int*   dst     = (const int*)d_in[5];
    float* out = (float*)d_out;
    char* ws = (char*)d_ws;

    float*          s       = (float*)(ws);
    float*          dd      = (float*)(ws + 200000);
    int*            cnt     = (int*)  (ws + 400000);
    int*            bin_cnt = (int*)  (ws + 600000);
    int*            ovf_cnt = (int*)  (ws + 650048);
    unsigned*       ovf     = (unsigned*)(ws + 650112);
    unsigned short* bucket  = (unsigned short*)(ws + 654208);
    unsigned*       binned  = (unsigned*)(ws + 5554208);
    unsigned short* fb      = (unsigned short*)(ws + 12761120);

    k_prep<<<(N_NODES * 64) / 256, 256, 0, stream>>>(
        feature, attn_w, s, dd, bin_cnt, ovf_cnt, fb);
    k_bin<<<NTILE, 256, 0, stream>>>(src, dst, bin_cnt, binned);
    k_fused<<<NBIN, 256, 0, stream>>>(
        binned, bin_cnt, cnt, bucket, ovf_cnt, ovf, s, dd, fb,
        lin_w, lin_b, out);
    k_cleanup<<<1, 256, 0, stream>>>(
        bucket, cnt, ovf_cnt, ovf, s, dd, feature, lin_w, lin_b, out);
}